// Round 1
// baseline (114.396 us; speedup 1.0000x reference)
//
#include <hip/hip_runtime.h>

namespace {
constexpr int BB = 2;
constexpr int NN = 50000;
constexpr int KK = 16;
constexpr int CI = 64;
constexpr int CO = 32;
constexpr int MM = 4;
constexpr int BN = BB * NN;            // 100000 nodes total
constexpr int WPB = 4;                 // waves per block
constexpr int NODE_GROUPS = BN / WPB;  // 25000
}

// K1: ux[bn][m] = u[m]·x[bn], vx[bn][m] = v[m]·x[bn]
__global__ __launch_bounds__(256) void k_uxvx(
    const float* __restrict__ x, const float* __restrict__ u,
    const float* __restrict__ v, float* __restrict__ ux,
    float* __restrict__ vx) {
  int idx = blockIdx.x * 256 + threadIdx.x;
  if (idx >= BN) return;
  const float4* xr = (const float4*)(x + (size_t)idx * CI);
  float su[MM] = {0.f, 0.f, 0.f, 0.f};
  float sv[MM] = {0.f, 0.f, 0.f, 0.f};
#pragma unroll
  for (int t = 0; t < CI / 4; ++t) {
    float4 xv = xr[t];
#pragma unroll
    for (int m = 0; m < MM; ++m) {
      float4 uv = *(const float4*)(u + m * CI + t * 4);
      float4 vv = *(const float4*)(v + m * CI + t * 4);
      su[m] += uv.x * xv.x + uv.y * xv.y + uv.z * xv.z + uv.w * xv.w;
      sv[m] += vv.x * xv.x + vv.y * xv.y + vv.z * xv.z + vv.w * xv.w;
    }
  }
  ((float4*)ux)[idx] = make_float4(su[0], su[1], su[2], su[3]);
  ((float4*)vx)[idx] = make_float4(sv[0], sv[1], sv[2], sv[3]);
}

// K2: one wave per node. lane = channel for gather/accumulate;
//     lane = (o, half-of-m) for the 32x256 output matmul from LDS.
__global__ __launch_bounds__(256) void k_main(
    const float* __restrict__ x, const int* __restrict__ adj,
    const float* __restrict__ weight, const float* __restrict__ bias,
    const float* __restrict__ cvec, const float* __restrict__ ux,
    const float* __restrict__ vx, float* __restrict__ out) {
  __shared__ float w_lds[MM][CO][CI + 4];  // stride 68 floats: rows stay 16B-aligned
  __shared__ float q_lds[WPB][64];
  __shared__ float t_lds[WPB][MM][CI];

  const int tid = threadIdx.x;
  const int lane = tid & 63;
  const int wv = tid >> 6;

  // stage weight[m][o][c] -> LDS (once per persistent block)
#pragma unroll
  for (int i = 0; i < (MM * CO * CI) / 256; ++i) {
    int g = i * 256 + tid;
    int m = g >> 11;
    int o = (g >> 6) & (CO - 1);
    int c = g & (CI - 1);
    w_lds[m][o][c] = weight[g];
  }
  __syncthreads();

  const int k4 = lane >> 2;   // neighbor slot for softmax phase
  const int m4 = lane & 3;    // mixture index for softmax phase
  const int o = lane & 31;    // output channel for matmul phase
  const int h = lane >> 5;    // m-half for matmul phase
  const int rot = o >> 2;     // bank-conflict rotation
  const float cm = cvec[m4];
  const float bo = bias[o];

  for (int g = blockIdx.x; g < NODE_GROUPS; g += gridDim.x) {
    const int bn = g * WPB + wv;
    const int b = (bn >= NN) ? 1 : 0;
    const int* adjp = adj + (size_t)bn * KK;
    const float* xb = x + (size_t)b * NN * CI;

    // adjacency (uniform per wave; 0 == empty slot, j>0 -> node j-1)
    int4 A[4];
#pragma unroll
    for (int i = 0; i < 4; ++i) A[i] = ((const int4*)adjp)[i];
    int deg = 0;
#pragma unroll
    for (int i = 0; i < 4; ++i)
      deg += (A[i].x != 0) + (A[i].y != 0) + (A[i].z != 0) + (A[i].w != 0);
    const float inv_deg = (deg > 0) ? 1.0f / (float)deg : 0.0f;

    // softmax gate q[k][m], lane = k*4+m; zero q for empty slots
    int a = adjp[k4];
    float vg = 0.f;
    if (a != 0) vg = vx[((size_t)b * NN + (a - 1)) * MM + m4];
    float logit = vg + ux[(size_t)bn * MM + m4] + cm;
    float mx = fmaxf(logit, __shfl_xor(logit, 1));
    mx = fmaxf(mx, __shfl_xor(mx, 2));
    float e = __expf(logit - mx);
    float s = e + __shfl_xor(e, 1);
    s += __shfl_xor(s, 2);
    float q = (a != 0) ? (e / s) : 0.f;
    q_lds[wv][lane] = q;

    // gather neighbor rows (coalesced 256B each), issued up-front
    int rows[KK];
    {
      int tmp[KK] = {A[0].x, A[0].y, A[0].z, A[0].w, A[1].x, A[1].y,
                     A[1].z, A[1].w, A[2].x, A[2].y, A[2].z, A[2].w,
                     A[3].x, A[3].y, A[3].z, A[3].w};
#pragma unroll
      for (int k = 0; k < KK; ++k) rows[k] = (tmp[k] != 0) ? (tmp[k] - 1) : 0;
    }
    float xg[KK];
#pragma unroll
    for (int k = 0; k < KK; ++k) xg[k] = xb[(size_t)rows[k] * CI + lane];

    // t[m][c] = sum_k q[k][m] * x_nbr[k][c]   (lane = c)
    float tacc[MM] = {0.f, 0.f, 0.f, 0.f};
#pragma unroll
    for (int k = 0; k < KK; ++k) {
      float4 qv = *(const float4*)&q_lds[wv][k * 4];  // broadcast read
      tacc[0] += qv.x * xg[k];
      tacc[1] += qv.y * xg[k];
      tacc[2] += qv.z * xg[k];
      tacc[3] += qv.w * xg[k];
    }
#pragma unroll
    for (int m = 0; m < MM; ++m) t_lds[wv][m][lane] = tacc[m];
    // same-wave DS ops are in-order: no barrier needed (per-wave LDS slices)

    // out[o] = sum_{m,c} w[m][o][c] * t[m][c]; each lane does 2 of 4 m's
    float acc = 0.f;
#pragma unroll
    for (int mm = 0; mm < 2; ++mm) {
      const float* wrow = &w_lds[2 * h + mm][o][0];
      const float* trow = &t_lds[wv][2 * h + mm][0];
#pragma unroll
      for (int t4 = 0; t4 < CI / 4; ++t4) {
        int tt = (t4 + rot) & 15;  // rotate to spread banks
        float4 wvv = *(const float4*)(wrow + 4 * tt);
        float4 tv = *(const float4*)(trow + 4 * tt);
        acc += wvv.x * tv.x + wvv.y * tv.y + wvv.z * tv.z + wvv.w * tv.w;
      }
    }
    acc += __shfl_xor(acc, 32);  // combine the two m-halves
    if (lane < 32) out[(size_t)bn * CO + o] = acc * inv_deg + bo;
  }
}

extern "C" void kernel_launch(void* const* d_in, const int* in_sizes, int n_in,
                              void* d_out, int out_size, void* d_ws,
                              size_t ws_size, hipStream_t stream) {
  const float* x = (const float*)d_in[0];
  const int* adj = (const int*)d_in[1];
  const float* weight = (const float*)d_in[2];
  const float* bias = (const float*)d_in[3];
  const float* u = (const float*)d_in[4];
  const float* v = (const float*)d_in[5];
  const float* cvec = (const float*)d_in[6];
  float* out = (float*)d_out;

  float* ux = (float*)d_ws;                 // BN*4 floats
  float* vx = ux + (size_t)BN * MM;         // BN*4 floats (3.2 MB total)

  k_uxvx<<<(BN + 255) / 256, 256, 0, stream>>>(x, u, v, ux, vx);
  k_main<<<1024, 256, 0, stream>>>(x, adj, weight, bias, cvec, ux, vx, out);
}